// Round 1
// baseline (896.915 us; speedup 1.0000x reference)
//
#include <hip/hip_runtime.h>
#include <math.h>

#define NEG_SLOPE 0.2f

typedef float f4 __attribute__((ext_vector_type(4)));

// ---------------- CSR build ----------------
__global__ void hist_kernel(const int* __restrict__ ei, int E, int Et, int* __restrict__ deg) {
    int e = blockIdx.x * blockDim.x + threadIdx.x;
    if (e >= Et) return;
    int d = (e < E) ? ei[E + e] : (e - E);   // self-loop edges appended
    atomicAdd(&deg[d], 1);
}

__global__ void scan_kernel(const int* __restrict__ deg, int* __restrict__ off, int n) {
    __shared__ int s_w[17];
    __shared__ int s_carry;
    int tid = threadIdx.x, lane = tid & 63, w = tid >> 6;
    if (tid == 0) s_carry = 0;
    __syncthreads();
    for (int base = 0; base < n; base += 1024) {
        int i = base + tid;
        int v = (i < n) ? deg[i] : 0;
        int x = v;
        #pragma unroll
        for (int d = 1; d < 64; d <<= 1) {
            int y = __shfl_up(x, d);
            if (lane >= d) x += y;
        }
        if (lane == 63) s_w[w] = x;
        __syncthreads();
        if (tid < 16) {
            int y = s_w[tid];
            int z = y;
            #pragma unroll
            for (int d = 1; d < 16; d <<= 1) {
                int t2 = __shfl_up(z, d);
                if (tid >= d) z += t2;
            }
            s_w[tid] = z - y;          // exclusive wave offset
            if (tid == 15) s_w[16] = z; // chunk total
        }
        __syncthreads();
        if (i < n) off[i] = s_carry + s_w[w] + (x - v);
        __syncthreads();
        if (tid == 0) s_carry += s_w[16];
        __syncthreads();
    }
    if (threadIdx.x == 0) off[n] = s_carry;
}

__global__ void copy_kernel(const int* __restrict__ src, int* __restrict__ dst, int n) {
    int i = blockIdx.x * blockDim.x + threadIdx.x;
    if (i < n) dst[i] = src[i];
}

__global__ void scatter_kernel(const int* __restrict__ ei, int E, int Et,
                               int* __restrict__ cur, int* __restrict__ csr) {
    int e = blockIdx.x * blockDim.x + threadIdx.x;
    if (e >= Et) return;
    int s, d;
    if (e < E) { s = ei[e]; d = ei[E + e]; }
    else       { s = d = e - E; }
    int p = atomicAdd(&cur[d], 1);
    csr[p] = s;
}

// ---------------- fp32 tiled GEMM: C[M,Nc] = A[M,K] @ B[K,Nc] ----------------
__global__ __launch_bounds__(256) void gemm_kernel(const float* __restrict__ A,
                                                   const float* __restrict__ B,
                                                   float* __restrict__ C,
                                                   int M, int K, int Nc) {
    __shared__ __align__(16) float As[16][68];   // [kk][row], padded stride 68 (16B aligned rows)
    __shared__ __align__(16) float Bs[16][64];   // [kk][col]
    int t  = threadIdx.x;
    int tc = t & 15, tr = t >> 4;
    int r0 = blockIdx.x * 64, c0 = blockIdx.y * 64;
    int arow = t >> 2, akq = t & 3;   // A loader: 64 rows x 16 k (float4 per thread)
    int bk   = t >> 4, bcq = t & 15;  // B loader: 16 k x 64 cols (float4 per thread)
    float acc[4][4] = {{0.f}};
    for (int k0 = 0; k0 < K; k0 += 16) {
        f4 av = {0.f, 0.f, 0.f, 0.f};
        int gr = r0 + arow;
        if (gr < M) av = *(const f4*)&A[(size_t)gr * K + k0 + akq * 4];
        f4 bv = *(const f4*)&B[(size_t)(k0 + bk) * Nc + c0 + bcq * 4];
        __syncthreads();
        #pragma unroll
        for (int u = 0; u < 4; u++) As[akq * 4 + u][arow] = av[u];
        *(f4*)&Bs[bk][bcq * 4] = bv;
        __syncthreads();
        #pragma unroll
        for (int kk = 0; kk < 16; kk++) {
            f4 a = *(const f4*)&As[kk][tr * 4];
            f4 b = *(const f4*)&Bs[kk][tc * 4];
            #pragma unroll
            for (int ir = 0; ir < 4; ir++)
                #pragma unroll
                for (int ic = 0; ic < 4; ic++)
                    acc[ir][ic] += a[ir] * b[ic];
        }
    }
    #pragma unroll
    for (int ir = 0; ir < 4; ir++) {
        int r = r0 + tr * 4 + ir;
        if (r < M) {
            f4 v = {acc[ir][0], acc[ir][1], acc[ir][2], acc[ir][3]};
            *(f4*)&C[(size_t)r * Nc + c0 + tc * 4] = v;
        }
    }
}

// ---------------- per-node attention dot products ----------------
template<int H, int TOT>
__global__ __launch_bounds__(256) void avec_kernel(const float* __restrict__ feat,
                                                   const float* __restrict__ aw_src,
                                                   const float* __restrict__ aw_dst,
                                                   float* __restrict__ out_src,
                                                   float* __restrict__ out_dst, int n) {
    constexpr int J = TOT / 64;
    constexpr int CPH = TOT / H;
    int w = threadIdx.x >> 6, lane = threadIdx.x & 63;
    int node = blockIdx.x * 4 + w;
    if (node >= n) return;
    float p[H], q[H];
    #pragma unroll
    for (int h = 0; h < H; h++) { p[h] = 0.f; q[h] = 0.f; }
    #pragma unroll
    for (int j = 0; j < J; j++) {
        int ch = lane + 64 * j;
        const int h = (64 * j) / CPH;   // lane-independent since CPH % 64 == 0
        float v = feat[(size_t)node * TOT + ch];
        p[h] += v * aw_src[ch];
        q[h] += v * aw_dst[ch];
    }
    #pragma unroll
    for (int h = 0; h < H; h++) {
        #pragma unroll
        for (int d = 32; d; d >>= 1) {
            p[h] += __shfl_xor(p[h], d);
            q[h] += __shfl_xor(q[h], d);
        }
    }
    if (lane == 0) {
        #pragma unroll
        for (int h = 0; h < H; h++) {
            out_src[(size_t)node * H + h] = p[h];
            out_dst[(size_t)node * H + h] = q[h];
        }
    }
}

// ---------------- edge softmax + aggregation (wave per dst), fused bias+ELU ----------------
template<int H, int TOT>
__global__ __launch_bounds__(256) void agg_kernel(const int* __restrict__ off,
                                                  const int* __restrict__ csr,
                                                  const float* __restrict__ feat,
                                                  const float* __restrict__ avs,
                                                  const float* __restrict__ avd,
                                                  const float* __restrict__ bias,
                                                  float* __restrict__ outf, int n) {
    constexpr int J = TOT / 64;
    constexpr int CPH = TOT / H;
    int w = threadIdx.x >> 6, lane = threadIdx.x & 63;
    int dst = blockIdx.x * 4 + w;
    if (dst >= n) return;
    int beg = off[dst], end = off[dst + 1];
    float ad[H];
    #pragma unroll
    for (int h = 0; h < H; h++) ad[h] = avd[(size_t)dst * H + h];
    // pass 1: per-head max logit
    float m[H];
    #pragma unroll
    for (int h = 0; h < H; h++) m[h] = -INFINITY;
    for (int e = beg + lane; e < end; e += 64) {
        int s = csr[e];
        #pragma unroll
        for (int h = 0; h < H; h++) {
            float l = avs[(size_t)s * H + h] + ad[h];
            l = l > 0.f ? l : NEG_SLOPE * l;
            m[h] = fmaxf(m[h], l);
        }
    }
    #pragma unroll
    for (int h = 0; h < H; h++)
        #pragma unroll
        for (int d = 32; d; d >>= 1) m[h] = fmaxf(m[h], __shfl_xor(m[h], d));
    // pass 2: denominator
    float den[H];
    #pragma unroll
    for (int h = 0; h < H; h++) den[h] = 0.f;
    for (int e = beg + lane; e < end; e += 64) {
        int s = csr[e];
        #pragma unroll
        for (int h = 0; h < H; h++) {
            float l = avs[(size_t)s * H + h] + ad[h];
            l = l > 0.f ? l : NEG_SLOPE * l;
            den[h] += __expf(l - m[h]);
        }
    }
    #pragma unroll
    for (int h = 0; h < H; h++) {
        #pragma unroll
        for (int d = 32; d; d >>= 1) den[h] += __shfl_xor(den[h], d);
    }
    float rden[H];
    #pragma unroll
    for (int h = 0; h < H; h++) rden[h] = 1.f / den[h];
    // pass 3: weighted aggregation; lane owns channels lane+64*j
    float acc[J];
    #pragma unroll
    for (int j = 0; j < J; j++) acc[j] = 0.f;
    for (int e = beg; e < end; e++) {
        int s = csr[e];
        float al[H];
        #pragma unroll
        for (int h = 0; h < H; h++) {
            float l = avs[(size_t)s * H + h] + ad[h];
            l = l > 0.f ? l : NEG_SLOPE * l;
            al[h] = __expf(l - m[h]) * rden[h];
        }
        #pragma unroll
        for (int j = 0; j < J; j++) {
            const int h = (64 * j) / CPH;
            acc[j] += al[h] * feat[(size_t)s * TOT + lane + 64 * j];
        }
    }
    // epilogue: + bias, ELU
    #pragma unroll
    for (int j = 0; j < J; j++) {
        int ch = lane + 64 * j;
        float v = acc[j] + bias[ch];
        v = v > 0.f ? v : expm1f(v);
        outf[(size_t)dst * TOT + ch] = v;
    }
}

// ---------------- pooling + head ----------------
__global__ __launch_bounds__(256) void pool_kernel(const float* __restrict__ feat,
                                                   const int* __restrict__ batch,
                                                   float* __restrict__ gsum,
                                                   int* __restrict__ gcnt, int n) {
    int w = threadIdx.x >> 6, lane = threadIdx.x & 63;
    int node = blockIdx.x * 4 + w;
    if (node >= n) return;
    int g = batch[node];
    #pragma unroll
    for (int j = 0; j < 2; j++) {
        int ch = lane + 64 * j;
        atomicAdd(&gsum[(size_t)g * 128 + ch], feat[(size_t)node * 128 + ch]);
    }
    if (lane == 0) atomicAdd(&gcnt[g], 1);
}

__global__ __launch_bounds__(256) void final_kernel(const float* __restrict__ gsum,
                                                    const int* __restrict__ gcnt,
                                                    const float* __restrict__ Wl,
                                                    const float* __restrict__ bl,
                                                    float* __restrict__ out, int g_total) {
    int w = threadIdx.x >> 6, lane = threadIdx.x & 63;
    int g = blockIdx.x * 4 + w;
    if (g >= g_total) return;
    float inv = 1.f / fmaxf((float)gcnt[g], 1.f);
    float p = 0.f;
    #pragma unroll
    for (int j = 0; j < 2; j++) {
        int ch = lane + 64 * j;
        p += gsum[(size_t)g * 128 + ch] * Wl[ch];
    }
    #pragma unroll
    for (int d = 32; d; d >>= 1) p += __shfl_xor(p, d);
    if (lane == 0) out[g] = p * inv + bl[0];
}

extern "C" void kernel_launch(void* const* d_in, const int* in_sizes, int n_in,
                              void* d_out, int out_size, void* d_ws, size_t ws_size,
                              hipStream_t stream) {
    const float* x   = (const float*)d_in[0];
    const int*   ei  = (const int*)d_in[1];
    const int*   bat = (const int*)d_in[2];
    const float* W1  = (const float*)d_in[3];
    const float* as1 = (const float*)d_in[4];
    const float* ad1 = (const float*)d_in[5];
    const float* b1  = (const float*)d_in[6];
    const float* W2  = (const float*)d_in[7];
    const float* as2 = (const float*)d_in[8];
    const float* ad2 = (const float*)d_in[9];
    const float* b2  = (const float*)d_in[10];
    const float* Wl  = (const float*)d_in[11];
    const float* bl  = (const float*)d_in[12];
    float* out = (float*)d_out;

    const int N  = in_sizes[0] / 128;
    const int E  = in_sizes[1] / 2;
    const int Et = E + N;
    const int G  = 512;

    char* p = (char*)d_ws;
    auto alloc = [&](size_t bytes) { char* r = p; p += (bytes + 255) & ~(size_t)255; return r; };
    float* h1   = (float*)alloc((size_t)N * 512 * 4);
    float* hbuf = (float*)alloc((size_t)N * 512 * 4);
    float* avs1 = (float*)alloc((size_t)N * 4 * 4);
    float* avd1 = (float*)alloc((size_t)N * 4 * 4);
    float* avs2 = (float*)alloc((size_t)N * 4);
    float* avd2 = (float*)alloc((size_t)N * 4);
    float* gsum = (float*)alloc((size_t)G * 128 * 4 + G * 4);  // gcnt appended
    int*   gcnt = (int*)(gsum + (size_t)G * 128);
    int*   deg  = (int*)alloc((size_t)N * 4);
    int*   off  = (int*)alloc((size_t)(N + 1) * 4);
    int*   cur  = (int*)alloc((size_t)N * 4);
    int*   csr  = (int*)alloc((size_t)Et * 4);
    float* h2    = h1;                       // reuse h1 region after layer 1
    float* feat2 = h1 + (size_t)N * 128;

    hipMemsetAsync(deg, 0, (size_t)N * 4, stream);
    hipMemsetAsync(gsum, 0, (size_t)G * 128 * 4 + G * 4, stream);

    // CSR by dst (reused for both layers)
    hist_kernel<<<(Et + 255) / 256, 256, 0, stream>>>(ei, E, Et, deg);
    scan_kernel<<<1, 1024, 0, stream>>>(deg, off, N);
    copy_kernel<<<(N + 255) / 256, 256, 0, stream>>>(off, cur, N);
    scatter_kernel<<<(Et + 255) / 256, 256, 0, stream>>>(ei, E, Et, cur, csr);

    // Layer 1
    gemm_kernel<<<dim3((N + 63) / 64, 8), 256, 0, stream>>>(x, W1, h1, N, 128, 512);
    avec_kernel<4, 512><<<(N + 3) / 4, 256, 0, stream>>>(h1, as1, ad1, avs1, avd1, N);
    agg_kernel<4, 512><<<(N + 3) / 4, 256, 0, stream>>>(off, csr, h1, avs1, avd1, b1, hbuf, N);

    // Layer 2
    gemm_kernel<<<dim3((N + 63) / 64, 2), 256, 0, stream>>>(hbuf, W2, h2, N, 512, 128);
    avec_kernel<1, 128><<<(N + 3) / 4, 256, 0, stream>>>(h2, as2, ad2, avs2, avd2, N);
    agg_kernel<1, 128><<<(N + 3) / 4, 256, 0, stream>>>(off, csr, h2, avs2, avd2, b2, feat2, N);

    // Pool + head
    pool_kernel<<<(N + 3) / 4, 256, 0, stream>>>(feat2, bat, gsum, gcnt, N);
    final_kernel<<<(G + 3) / 4, 256, 0, stream>>>(gsum, gcnt, Wl, bl, out, G);
}

// Round 2
// 600.843 us; speedup vs baseline: 1.4928x; 1.4928x over previous
//
#include <hip/hip_runtime.h>
#include <math.h>

#define NEG_SLOPE 0.2f

typedef float f4 __attribute__((ext_vector_type(4)));
typedef __attribute__((ext_vector_type(8))) short short8;   // 8 bf16 (4 VGPRs)
typedef __attribute__((ext_vector_type(4))) float f32x4;
typedef unsigned short ushort_t;

__device__ __forceinline__ float bf2f(unsigned short s) {
    unsigned u = ((unsigned)s) << 16;
    float f; __builtin_memcpy(&f, &u, 4); return f;
}
__device__ __forceinline__ unsigned short f2bf(float f) {
    unsigned u; __builtin_memcpy(&u, &f, 4);
    u = (u + 0x7FFFu + ((u >> 16) & 1u)) >> 16;   // RNE
    return (unsigned short)u;
}
__device__ __forceinline__ void gload16(const void* g, void* l) {
    __builtin_amdgcn_global_load_lds((const __attribute__((address_space(1))) void*)g,
                                     (__attribute__((address_space(3))) void*)l, 16, 0, 0);
}

// ---------------- CSR build ----------------
__global__ void hist_kernel(const int* __restrict__ ei, int E, int Et, int* __restrict__ deg) {
    int e = blockIdx.x * blockDim.x + threadIdx.x;
    if (e >= Et) return;
    int d = (e < E) ? ei[E + e] : (e - E);
    atomicAdd(&deg[d], 1);
}

__global__ void scan_kernel(const int* __restrict__ deg, int* __restrict__ off, int n) {
    __shared__ int s_w[17];
    __shared__ int s_carry;
    int tid = threadIdx.x, lane = tid & 63, w = tid >> 6;
    if (tid == 0) s_carry = 0;
    __syncthreads();
    for (int base = 0; base < n; base += 1024) {
        int i = base + tid;
        int v = (i < n) ? deg[i] : 0;
        int x = v;
        #pragma unroll
        for (int d = 1; d < 64; d <<= 1) {
            int y = __shfl_up(x, d);
            if (lane >= d) x += y;
        }
        if (lane == 63) s_w[w] = x;
        __syncthreads();
        if (tid < 16) {
            int y = s_w[tid];
            int z = y;
            #pragma unroll
            for (int d = 1; d < 16; d <<= 1) {
                int t2 = __shfl_up(z, d);
                if (tid >= d) z += t2;
            }
            s_w[tid] = z - y;
            if (tid == 15) s_w[16] = z;
        }
        __syncthreads();
        if (i < n) off[i] = s_carry + s_w[w] + (x - v);
        __syncthreads();
        if (tid == 0) s_carry += s_w[16];
        __syncthreads();
    }
    if (threadIdx.x == 0) off[n] = s_carry;
}

__global__ void copy_kernel(const int* __restrict__ src, int* __restrict__ dst, int n) {
    int i = blockIdx.x * blockDim.x + threadIdx.x;
    if (i < n) dst[i] = src[i];
}

__global__ void scatter_kernel(const int* __restrict__ ei, int E, int Et,
                               int* __restrict__ cur, int* __restrict__ csr) {
    int e = blockIdx.x * blockDim.x + threadIdx.x;
    if (e >= Et) return;
    int s, d;
    if (e < E) { s = ei[e]; d = ei[E + e]; }
    else       { s = d = e - E; }
    int p = atomicAdd(&cur[d], 1);
    csr[p] = s;
}

// ---------------- casts ----------------
__global__ void cast_x_kernel(const float* __restrict__ x, ushort_t* __restrict__ xb,
                              int n_elts, int pad_elts) {
    int i = blockIdx.x * blockDim.x + threadIdx.x;
    if (i >= pad_elts) return;
    float v = (i < n_elts) ? x[i] : 0.f;
    xb[i] = f2bf(v);
}

__global__ void transpose_cast_kernel(const float* __restrict__ W, ushort_t* __restrict__ Wt,
                                      int K, int Nc) {
    int i = blockIdx.x * blockDim.x + threadIdx.x;
    if (i >= K * Nc) return;
    int k = i / Nc, n2 = i - k * Nc;
    Wt[(size_t)n2 * K + k] = f2bf(W[i]);
}

// ---------------- bf16 MFMA GEMM: C[M,Nc] = A[M,K] @ Bt[Nc,K]^T, all bf16, fp32 acc ----------------
// 128x128 tile, BK=32, 4 waves in 2x2, each wave 64x64 via 4x4 of 16x16x32 MFMAs.
__global__ __launch_bounds__(256) void gemm_bf16(const ushort_t* __restrict__ A,
                                                 const ushort_t* __restrict__ Bt,
                                                 ushort_t* __restrict__ C,
                                                 int M, int K, int Nc) {
    __shared__ __align__(16) ushort_t As[128 * 32];
    __shared__ __align__(16) ushort_t Bs[128 * 32];
    const int t = threadIdx.x, w = t >> 6, lane = t & 63;
    const int r0 = blockIdx.x * 128, c0 = blockIdx.y * 128;
    const int wr = w & 1, wc = w >> 1;

    // staging: wave w stages rows w*32 .. w*32+31 (16 rows per global_load_lds inst)
    const ushort_t* Ag0 = A + (size_t)(r0 + w * 32 + (lane >> 2)) * K + (lane & 3) * 8;
    const ushort_t* Bg0 = Bt + (size_t)(c0 + w * 32 + (lane >> 2)) * K + (lane & 3) * 8;
    ushort_t* Al0 = As + w * 1024;          // wave-uniform LDS base; HW adds lane*16B
    ushort_t* Bl0 = Bs + w * 1024;

    f32x4 acc[4][4] = {};
    for (int k0 = 0; k0 < K; k0 += 32) {
        __syncthreads();
        gload16(Ag0 + k0, Al0);
        gload16(Ag0 + k0 + (size_t)16 * K, Al0 + 512);
        gload16(Bg0 + k0, Bl0);
        gload16(Bg0 + k0 + (size_t)16 * K, Bl0 + 512);
        __syncthreads();
        short8 af[4], bf[4];
        #pragma unroll
        for (int i = 0; i < 4; i++) {
            int m = wr * 64 + i * 16 + (lane & 15);
            int nn = wc * 64 + i * 16 + (lane & 15);
            af[i] = *(const short8*)(As + m * 32 + (lane >> 4) * 8);
            bf[i] = *(const short8*)(Bs + nn * 32 + (lane >> 4) * 8);
        }
        #pragma unroll
        for (int i = 0; i < 4; i++)
            #pragma unroll
            for (int jj = 0; jj < 4; jj++)
                acc[i][jj] = __builtin_amdgcn_mfma_f32_16x16x32_bf16(af[i], bf[jj], acc[i][jj], 0, 0, 0);
    }
    // epilogue: C/D layout col=lane&15, row=(lane>>4)*4+reg
    #pragma unroll
    for (int i = 0; i < 4; i++) {
        #pragma unroll
        for (int jj = 0; jj < 4; jj++) {
            #pragma unroll
            for (int r = 0; r < 4; r++) {
                int row = r0 + wr * 64 + i * 16 + (lane >> 4) * 4 + r;
                int col = c0 + wc * 64 + jj * 16 + (lane & 15);
                C[(size_t)row * Nc + col] = f2bf(acc[i][jj][r]);
            }
        }
    }
}

// ---------------- per-node attention dot products (bf16 feat) ----------------
template<int H, int TOT>
__global__ __launch_bounds__(256) void avec_kernel(const ushort_t* __restrict__ feat,
                                                   const float* __restrict__ aw_src,
                                                   const float* __restrict__ aw_dst,
                                                   float* __restrict__ out_src,
                                                   float* __restrict__ out_dst, int n) {
    constexpr int J = TOT / 64;
    constexpr int GL = (TOT / H) / J;      // lanes per head group
    int w = threadIdx.x >> 6, lane = threadIdx.x & 63;
    int node = blockIdx.x * 4 + w;
    if (node >= n) return;
    float p = 0.f, q = 0.f;
    #pragma unroll
    for (int u = 0; u < J; u++) {
        int ch = lane * J + u;
        float v = bf2f(feat[(size_t)node * TOT + ch]);
        p += v * aw_src[ch];
        q += v * aw_dst[ch];
    }
    #pragma unroll
    for (int d = 1; d < GL; d <<= 1) {
        p += __shfl_xor(p, d);
        q += __shfl_xor(q, d);
    }
    if ((lane & (GL - 1)) == 0) {
        int h = lane / GL;
        out_src[(size_t)node * H + h] = p;
        out_dst[(size_t)node * H + h] = q;
    }
}

// ---------------- single-pass edge softmax + aggregation (wave per dst) ----------------
// out = (sum_e exp(l_e) * feat[src_e]) / (sum_e exp(l_e));  bias+ELU fused.
template<int H, int TOT, bool OUT_BF16>
__global__ __launch_bounds__(256) void agg_kernel(const int* __restrict__ off,
                                                  const int* __restrict__ csr,
                                                  const ushort_t* __restrict__ feat,
                                                  const float* __restrict__ avs,
                                                  const float* __restrict__ avd,
                                                  const float* __restrict__ bias,
                                                  void* __restrict__ outv, int n) {
    constexpr int J = TOT / 64;
    constexpr int CPH = TOT / H;
    int w = threadIdx.x >> 6, lane = threadIdx.x & 63;
    int dst = blockIdx.x * 4 + w;
    if (dst >= n) return;
    const int h_own = (lane * J) / CPH;
    const float ad_own = avd[(size_t)dst * H + h_own];
    int beg = off[dst], end = off[dst + 1];
    float den = 0.f;
    float acc[J] = {};
    for (int b = beg; b < end; b += 64) {
        int s_l = (b + lane < end) ? csr[b + lane] : 0;
        int cnt = min(64, end - b);
        for (int j = 0; j < cnt; j++) {
            int sv = __shfl(s_l, j);
            float a = avs[(size_t)sv * H + h_own];
            float l = a + ad_own;
            l = l > 0.f ? l : NEG_SLOPE * l;
            float ex = __expf(l);       // no max-subtraction: |l| <~ 6, safe in fp32
            den += ex;
            const ushort_t* fp = feat + (size_t)sv * TOT + lane * J;
            if constexpr (J == 8) {
                short8 fv = *(const short8*)fp;
                #pragma unroll
                for (int u = 0; u < 8; u++) acc[u] += ex * bf2f((unsigned short)fv[u]);
            } else {
                unsigned fv = *(const unsigned*)fp;
                acc[0] += ex * bf2f((unsigned short)(fv & 0xffffu));
                acc[1] += ex * bf2f((unsigned short)(fv >> 16));
            }
        }
    }
    float rden = 1.f / den;
    if constexpr (OUT_BF16) {
        unsigned short ov[J];
        #pragma unroll
        for (int u = 0; u < J; u++) {
            float v = acc[u] * rden + bias[lane * J + u];
            v = v > 0.f ? v : expm1f(v);
            ov[u] = f2bf(v);
        }
        *(short8*)((ushort_t*)outv + (size_t)dst * TOT + lane * J) = *(short8*)ov;
    } else {
        float v0 = acc[0] * rden + bias[lane * 2];
        float v1 = acc[1] * rden + bias[lane * 2 + 1];
        v0 = v0 > 0.f ? v0 : expm1f(v0);
        v1 = v1 > 0.f ? v1 : expm1f(v1);
        float2 vv = make_float2(v0, v1);
        *(float2*)((float*)outv + (size_t)dst * TOT + lane * 2) = vv;
    }
}

// ---------------- pooling + head ----------------
__global__ __launch_bounds__(256) void pool_kernel(const float* __restrict__ feat,
                                                   const int* __restrict__ batch,
                                                   float* __restrict__ gsum,
                                                   int* __restrict__ gcnt, int n) {
    int w = threadIdx.x >> 6, lane = threadIdx.x & 63;
    int node = blockIdx.x * 4 + w;
    if (node >= n) return;
    int g = batch[node];
    #pragma unroll
    for (int j = 0; j < 2; j++) {
        int ch = lane + 64 * j;
        atomicAdd(&gsum[(size_t)g * 128 + ch], feat[(size_t)node * 128 + ch]);
    }
    if (lane == 0) atomicAdd(&gcnt[g], 1);
}

__global__ __launch_bounds__(256) void final_kernel(const float* __restrict__ gsum,
                                                    const int* __restrict__ gcnt,
                                                    const float* __restrict__ Wl,
                                                    const float* __restrict__ bl,
                                                    float* __restrict__ out, int g_total) {
    int w = threadIdx.x >> 6, lane = threadIdx.x & 63;
    int g = blockIdx.x * 4 + w;
    if (g >= g_total) return;
    float inv = 1.f / fmaxf((float)gcnt[g], 1.f);
    float p = 0.f;
    #pragma unroll
    for (int j = 0; j < 2; j++) {
        int ch = lane + 64 * j;
        p += gsum[(size_t)g * 128 + ch] * Wl[ch];
    }
    #pragma unroll
    for (int d = 32; d; d >>= 1) p += __shfl_xor(p, d);
    if (lane == 0) out[g] = p * inv + bl[0];
}

extern "C" void kernel_launch(void* const* d_in, const int* in_sizes, int n_in,
                              void* d_out, int out_size, void* d_ws, size_t ws_size,
                              hipStream_t stream) {
    const float* x   = (const float*)d_in[0];
    const int*   ei  = (const int*)d_in[1];
    const int*   bat = (const int*)d_in[2];
    const float* W1  = (const float*)d_in[3];
    const float* as1 = (const float*)d_in[4];
    const float* ad1 = (const float*)d_in[5];
    const float* b1  = (const float*)d_in[6];
    const float* W2  = (const float*)d_in[7];
    const float* as2 = (const float*)d_in[8];
    const float* ad2 = (const float*)d_in[9];
    const float* b2  = (const float*)d_in[10];
    const float* Wl  = (const float*)d_in[11];
    const float* bl  = (const float*)d_in[12];
    float* out = (float*)d_out;

    const int N    = in_sizes[0] / 128;
    const int E    = in_sizes[1] / 2;
    const int Et   = E + N;
    const int G    = 512;
    const int Mpad = (N + 127) & ~127;

    char* p = (char*)d_ws;
    auto alloc = [&](size_t bytes) { char* r = p; p += (bytes + 255) & ~(size_t)255; return r; };
    ushort_t* xb   = (ushort_t*)alloc((size_t)Mpad * 128 * 2);
    ushort_t* W1t  = (ushort_t*)alloc((size_t)512 * 128 * 2);
    ushort_t* W2t  = (ushort_t*)alloc((size_t)128 * 512 * 2);
    ushort_t* h1b  = (ushort_t*)alloc((size_t)Mpad * 512 * 2);
    ushort_t* hb   = (ushort_t*)alloc((size_t)Mpad * 512 * 2);
    ushort_t* h2b  = (ushort_t*)alloc((size_t)Mpad * 128 * 2);
    float*    feat2= (float*)alloc((size_t)N * 128 * 4);
    float*    avs1 = (float*)alloc((size_t)N * 4 * 4);
    float*    avd1 = (float*)alloc((size_t)N * 4 * 4);
    float*    avs2 = (float*)alloc((size_t)N * 4);
    float*    avd2 = (float*)alloc((size_t)N * 4);
    float*    gsum = (float*)alloc((size_t)G * 128 * 4 + G * 4);
    int*      gcnt = (int*)(gsum + (size_t)G * 128);
    int*      deg  = (int*)alloc((size_t)N * 4);
    int*      off  = (int*)alloc((size_t)(N + 1) * 4);
    int*      cur  = (int*)alloc((size_t)N * 4);
    int*      csr  = (int*)alloc((size_t)Et * 4);

    hipMemsetAsync(deg, 0, (size_t)N * 4, stream);
    hipMemsetAsync(gsum, 0, (size_t)G * 128 * 4 + G * 4, stream);
    hipMemsetAsync(hb + (size_t)N * 512, 0, (size_t)(Mpad - N) * 512 * 2, stream);

    // CSR by dst (shared by both layers)
    hist_kernel<<<(Et + 255) / 256, 256, 0, stream>>>(ei, E, Et, deg);
    scan_kernel<<<1, 1024, 0, stream>>>(deg, off, N);
    copy_kernel<<<(N + 255) / 256, 256, 0, stream>>>(off, cur, N);
    scatter_kernel<<<(Et + 255) / 256, 256, 0, stream>>>(ei, E, Et, cur, csr);

    // casts
    cast_x_kernel<<<(Mpad * 128 + 255) / 256, 256, 0, stream>>>(x, xb, N * 128, Mpad * 128);
    transpose_cast_kernel<<<(128 * 512 + 255) / 256, 256, 0, stream>>>(W1, W1t, 128, 512);
    transpose_cast_kernel<<<(512 * 128 + 255) / 256, 256, 0, stream>>>(W2, W2t, 512, 128);

    // Layer 1
    gemm_bf16<<<dim3(Mpad / 128, 4), 256, 0, stream>>>(xb, W1t, h1b, Mpad, 128, 512);
    avec_kernel<4, 512><<<(N + 3) / 4, 256, 0, stream>>>(h1b, as1, ad1, avs1, avd1, N);
    agg_kernel<4, 512, true><<<(N + 3) / 4, 256, 0, stream>>>(off, csr, h1b, avs1, avd1, b1, hb, N);

    // Layer 2
    gemm_bf16<<<dim3(Mpad / 128, 1), 256, 0, stream>>>(hb, W2t, h2b, Mpad, 512, 128);
    avec_kernel<1, 128><<<(N + 3) / 4, 256, 0, stream>>>(h2b, as2, ad2, avs2, avd2, N);
    agg_kernel<1, 128, false><<<(N + 3) / 4, 256, 0, stream>>>(off, csr, h2b, avs2, avd2, b2, feat2, N);

    // Pool + head
    pool_kernel<<<(N + 3) / 4, 256, 0, stream>>>(feat2, bat, gsum, gcnt, N);
    final_kernel<<<(G + 3) / 4, 256, 0, stream>>>(gsum, gcnt, Wl, bl, out, G);
}

// Round 3
// 501.573 us; speedup vs baseline: 1.7882x; 1.1979x over previous
//
#include <hip/hip_runtime.h>
#include <math.h>

#define NEG_SLOPE 0.2f

typedef float f4 __attribute__((ext_vector_type(4)));
typedef __attribute__((ext_vector_type(8))) short short8;   // 8 bf16 (4 VGPRs)
typedef __attribute__((ext_vector_type(4))) float f32x4;
typedef unsigned short ushort_t;

__device__ __forceinline__ float bf2f(unsigned short s) {
    unsigned u = ((unsigned)s) << 16;
    float f; __builtin_memcpy(&f, &u, 4); return f;
}
__device__ __forceinline__ unsigned short f2bf(float f) {
    unsigned u; __builtin_memcpy(&u, &f, 4);
    u = (u + 0x7FFFu + ((u >> 16) & 1u)) >> 16;   // RNE
    return (unsigned short)u;
}
__device__ __forceinline__ void gload16(const void* g, void* l) {
    __builtin_amdgcn_global_load_lds((const __attribute__((address_space(1))) void*)g,
                                     (__attribute__((address_space(3))) void*)l, 16, 0, 0);
}

// ---------------- CSR build ----------------
__global__ void hist_kernel(const int* __restrict__ ei, int E, int Et, int* __restrict__ deg) {
    int e = blockIdx.x * blockDim.x + threadIdx.x;
    if (e >= Et) return;
    int d = (e < E) ? ei[E + e] : (e - E);
    atomicAdd(&deg[d], 1);
}

__global__ __launch_bounds__(1024) void scan_local(const int* __restrict__ deg,
                                                   int* __restrict__ off,
                                                   int* __restrict__ btot, int n) {
    __shared__ int s_w[16];
    int tid = threadIdx.x, lane = tid & 63, wv = tid >> 6;
    int i = blockIdx.x * 1024 + tid;
    int v = (i < n) ? deg[i] : 0;
    int x = v;
    #pragma unroll
    for (int d = 1; d < 64; d <<= 1) {
        int y = __shfl_up(x, d);
        if (lane >= d) x += y;
    }
    if (lane == 63) s_w[wv] = x;
    __syncthreads();
    if (tid < 16) {
        int y = s_w[tid];
        int z = y;
        #pragma unroll
        for (int d = 1; d < 16; d <<= 1) {
            int t2 = __shfl_up(z, d);
            if (tid >= d) z += t2;
        }
        if (tid == 15) btot[blockIdx.x] = z;   // chunk total
        s_w[tid] = z - y;                      // exclusive wave base
    }
    __syncthreads();
    if (i < n) off[i] = s_w[wv] + (x - v);     // chunk-local exclusive
}

__global__ void scan_base(int* __restrict__ btot, int nb) {
    int lane = threadIdx.x;   // 64 threads, nb <= 64
    int v = (lane < nb) ? btot[lane] : 0;
    int x = v;
    #pragma unroll
    for (int d = 1; d < 64; d <<= 1) {
        int y = __shfl_up(x, d);
        if (lane >= d) x += y;
    }
    int total = __shfl(x, nb - 1);
    if (lane < nb) btot[lane] = x - v;
    if (lane == 0) btot[nb] = total;
}

__global__ void scan_add(const int* __restrict__ btot, int* __restrict__ off,
                         int* __restrict__ cur, const int* __restrict__ batch,
                         int* __restrict__ gcnt, int n, int nb) {
    int i = blockIdx.x * blockDim.x + threadIdx.x;
    if (i < n) {
        int o = off[i] + btot[i >> 10];
        off[i] = o;
        cur[i] = o;
        atomicAdd(&gcnt[batch[i]], 1);   // wave-coalesced: batch sorted
    } else if (i == n) {
        off[n] = btot[nb];
    }
}

__global__ void scatter_kernel(const int* __restrict__ ei, int E, int Et,
                               int* __restrict__ cur, int* __restrict__ csr) {
    int e = blockIdx.x * blockDim.x + threadIdx.x;
    if (e >= Et) return;
    int s, d;
    if (e < E) { s = ei[e]; d = ei[E + e]; }
    else       { s = d = e - E; }
    int p = atomicAdd(&cur[d], 1);
    csr[p] = s;
}

// ---------------- fused casts: x -> bf16 (padded), W1/W2 -> transposed bf16 ----------------
__global__ void cast_all(const float* __restrict__ x, const float* __restrict__ W1,
                         const float* __restrict__ W2, ushort_t* __restrict__ xb,
                         ushort_t* __restrict__ W1t, ushort_t* __restrict__ W2t,
                         int n_x, int pad_x) {
    int i = blockIdx.x * blockDim.x + threadIdx.x;
    if (i < pad_x) {
        xb[i] = f2bf(i < n_x ? x[i] : 0.f);
        return;
    }
    int k = i - pad_x;
    if (k < 128 * 512) {                 // W1 [128][512] -> W1t [512][128]
        int r = k >> 9, c = k & 511;
        W1t[(size_t)c * 128 + r] = f2bf(W1[k]);
        return;
    }
    k -= 128 * 512;
    if (k < 512 * 128) {                 // W2 [512][128] -> W2t [128][512]
        int r = k >> 7, c = k & 127;
        W2t[(size_t)c * 512 + r] = f2bf(W2[k]);
    }
}

// ---------------- bf16 MFMA GEMM + fused attention-vector epilogue ----------------
// C[M,Nc] = A[M,K] @ Bt[Nc,K]^T. BM = MI*32 (MI=4 -> 128, MI=2 -> 64), BN=128, BK=32.
// Also: avs[row*H+head] += sum_col C[row,col]*aw_src[col] (head = col>>7), same for avd.
template<int MI, int H>
__global__ __launch_bounds__(256) void gemm_bf16(const ushort_t* __restrict__ A,
                                                 const ushort_t* __restrict__ Bt,
                                                 ushort_t* __restrict__ C,
                                                 const float* __restrict__ aw_src,
                                                 const float* __restrict__ aw_dst,
                                                 float* __restrict__ avs,
                                                 float* __restrict__ avd,
                                                 int K, int Nc) {
    constexpr int BM = MI * 32;
    constexpr int AI = MI / 2;           // A staging insts per wave (16 rows each)
    __shared__ __align__(16) ushort_t As[BM * 32];
    __shared__ __align__(16) ushort_t Bs[128 * 32];
    __shared__ __align__(16) ushort_t Cs[4 * MI * 16 * 72];   // padded stride 72 (144B, 16B-aligned)
    const int t = threadIdx.x, w = t >> 6, lane = t & 63;
    const int r0 = blockIdx.x * BM, c0 = blockIdx.y * 128;
    const int wr = w & 1, wc = w >> 1;

    const ushort_t* Ag = A + (size_t)(r0 + w * (BM / 4) + (lane >> 2)) * K + (lane & 3) * 8;
    const ushort_t* Bg = Bt + (size_t)(c0 + w * 32 + (lane >> 2)) * K + (lane & 3) * 8;
    ushort_t* Al = As + w * (BM / 4) * 32;
    ushort_t* Bl = Bs + w * 1024;

    f32x4 acc[MI][4] = {};
    for (int k0 = 0; k0 < K; k0 += 32) {
        __syncthreads();
        #pragma unroll
        for (int m = 0; m < AI; m++) gload16(Ag + k0 + (size_t)m * 16 * K, Al + m * 512);
        gload16(Bg + k0, Bl);
        gload16(Bg + k0 + (size_t)16 * K, Bl + 512);
        __syncthreads();
        short8 af[MI], bf[4];
        #pragma unroll
        for (int i = 0; i < MI; i++)
            af[i] = *(const short8*)(As + (wr * MI * 16 + i * 16 + (lane & 15)) * 32 + (lane >> 4) * 8);
        #pragma unroll
        for (int jj = 0; jj < 4; jj++)
            bf[jj] = *(const short8*)(Bs + (wc * 64 + jj * 16 + (lane & 15)) * 32 + (lane >> 4) * 8);
        #pragma unroll
        for (int i = 0; i < MI; i++)
            #pragma unroll
            for (int jj = 0; jj < 4; jj++)
                acc[i][jj] = __builtin_amdgcn_mfma_f32_16x16x32_bf16(af[i], bf[jj], acc[i][jj], 0, 0, 0);
    }

    // ---- fused avec: partial dot over this wave's 64 cols, reduce, atomicAdd ----
    const int head = c0 >> 7;            // block spans exactly one head (or H==1)
    float asc[4], adc[4];
    #pragma unroll
    for (int jj = 0; jj < 4; jj++) {
        int c = c0 + wc * 64 + jj * 16 + (lane & 15);
        asc[jj] = aw_src[c];
        adc[jj] = aw_dst[c];
    }
    #pragma unroll
    for (int i = 0; i < MI; i++) {
        #pragma unroll
        for (int r = 0; r < 4; r++) {
            float ps = 0.f, pd = 0.f;
            #pragma unroll
            for (int jj = 0; jj < 4; jj++) {
                float v = acc[i][jj][r];
                ps = fmaf(v, asc[jj], ps);
                pd = fmaf(v, adc[jj], pd);
            }
            #pragma unroll
            for (int d = 1; d < 16; d <<= 1) {
                ps += __shfl_xor(ps, d);
                pd += __shfl_xor(pd, d);
            }
            if ((lane & 15) == 0) {
                int row = r0 + wr * MI * 16 + i * 16 + (lane >> 4) * 4 + r;
                atomicAdd(&avs[(size_t)row * H + head], ps);
                atomicAdd(&avd[(size_t)row * H + head], pd);
            }
        }
    }

    // ---- coalesced C store via per-wave LDS staging ----
    ushort_t* Cw = Cs + w * (MI * 16 * 72);
    #pragma unroll
    for (int i = 0; i < MI; i++)
        #pragma unroll
        for (int jj = 0; jj < 4; jj++)
            #pragma unroll
            for (int r = 0; r < 4; r++)
                Cw[(i * 16 + (lane >> 4) * 4 + r) * 72 + jj * 16 + (lane & 15)] = f2bf(acc[i][jj][r]);
    asm volatile("s_waitcnt lgkmcnt(0)" ::: "memory");
    #pragma unroll
    for (int pass = 0; pass < MI * 2; pass++) {
        int row_l = pass * 8 + (lane >> 3);
        short8 v = *(const short8*)(Cw + row_l * 72 + (lane & 7) * 8);
        int grow = r0 + wr * MI * 16 + row_l;
        int gcol = c0 + wc * 64 + (lane & 7) * 8;
        *(short8*)(C + (size_t)grow * Nc + gcol) = v;
    }
}

// ---------------- single-pass edge softmax + aggregation (wave per dst) ----------------
// Chunked: each lane computes ONE edge's exp (not 64x redundant), stash in per-wave LDS,
// then a 2x-unrolled gather/FMA loop. out = num/den; bias+ELU fused.
template<int H, int TOT, bool OUT_BF16>
__global__ __launch_bounds__(256) void agg_kernel(const int* __restrict__ off,
                                                  const int* __restrict__ csr,
                                                  const ushort_t* __restrict__ feat,
                                                  const float* __restrict__ avs,
                                                  const float* __restrict__ avd,
                                                  const float* __restrict__ bias,
                                                  void* __restrict__ outv, int n) {
    constexpr int J = TOT / 64;
    __shared__ float s_ex[4][64 * H];
    __shared__ int   s_sv[4][64];
    int w = threadIdx.x >> 6, lane = threadIdx.x & 63;
    int dst = blockIdx.x * 4 + w;
    if (dst >= n) return;
    const int h_own = (lane * J) / (TOT / H);
    float adv[H];
    if constexpr (H == 4) {
        f4 t4 = *(const f4*)&avd[(size_t)dst * 4];
        #pragma unroll
        for (int h = 0; h < 4; h++) adv[h] = t4[h];
    } else {
        adv[0] = avd[dst];
    }
    int beg = off[dst], end = off[dst + 1];
    float den = 0.f;
    float acc[J] = {};
    float* exw = s_ex[w];
    int*   svw = s_sv[w];

    for (int b = beg; b < end; b += 64) {
        int idx = b + lane;
        bool val = idx < end;
        int sv = val ? csr[idx] : 0;
        svw[lane] = sv;
        if constexpr (H == 4) {
            f4 av = {};
            if (val) av = *(const f4*)&avs[(size_t)sv * 4];
            f4 exv;
            #pragma unroll
            for (int h = 0; h < 4; h++) {
                float l = av[h] + adv[h];
                l = l > 0.f ? l : NEG_SLOPE * l;
                exv[h] = val ? __expf(l) : 0.f;
            }
            *(f4*)&exw[lane * 4] = exv;
        } else {
            float l = (val ? avs[sv] : 0.f) + adv[0];
            l = l > 0.f ? l : NEG_SLOPE * l;
            exw[lane] = val ? __expf(l) : 0.f;
        }
        asm volatile("s_waitcnt lgkmcnt(0)" ::: "memory");
        int cnt = min(64, end - b);
        int j = 0;
        for (; j + 2 <= cnt; j += 2) {
            int   s0 = svw[j],              s1 = svw[j + 1];
            float e0 = exw[j * H + h_own],  e1 = exw[(j + 1) * H + h_own];
            den += e0 + e1;
            const ushort_t* f0 = feat + (size_t)s0 * TOT + lane * J;
            const ushort_t* f1 = feat + (size_t)s1 * TOT + lane * J;
            if constexpr (J == 8) {
                short8 v0 = *(const short8*)f0;
                short8 v1 = *(const short8*)f1;
                #pragma unroll
                for (int u = 0; u < 8; u++) acc[u] += e0 * bf2f((unsigned short)v0[u]);
                #pragma unroll
                for (int u = 0; u < 8; u++) acc[u] += e1 * bf2f((unsigned short)v1[u]);
            } else {
                unsigned v0 = *(const unsigned*)f0;
                unsigned v1 = *(const unsigned*)f1;
                acc[0] += e0 * bf2f((unsigned short)(v0 & 0xffffu));
                acc[1] += e0 * bf2f((unsigned short)(v0 >> 16));
                acc[0] += e1 * bf2f((unsigned short)(v1 & 0xffffu));
                acc[1] += e1 * bf2f((unsigned short)(v1 >> 16));
            }
        }
        if (j < cnt) {
            int   s0 = svw[j];
            float e0 = exw[j * H + h_own];
            den += e0;
            const ushort_t* f0 = feat + (size_t)s0 * TOT + lane * J;
            if constexpr (J == 8) {
                short8 v0 = *(const short8*)f0;
                #pragma unroll
                for (int u = 0; u < 8; u++) acc[u] += e0 * bf2f((unsigned short)v0[u]);
            } else {
                unsigned v0 = *(const unsigned*)f0;
                acc[0] += e0 * bf2f((unsigned short)(v0 & 0xffffu));
                acc[1] += e0 * bf2f((unsigned short)(v0 >> 16));
            }
        }
    }
    float rden = 1.f / den;
    if constexpr (OUT_BF16) {
        unsigned short ov[J];
        #pragma unroll
        for (int u = 0; u < J; u++) {
            float v = acc[u] * rden + bias[lane * J + u];
            v = v > 0.f ? v : expm1f(v);
            ov[u] = f2bf(v);
        }
        *(short8*)((ushort_t*)outv + (size_t)dst * TOT + lane * J) = *(short8*)ov;
    } else {
        float v0 = acc[0] * rden + bias[lane * 2];
        float v1 = acc[1] * rden + bias[lane * 2 + 1];
        v0 = v0 > 0.f ? v0 : expm1f(v0);
        v1 = v1 > 0.f ? v1 : expm1f(v1);
        float2 vv = make_float2(v0, v1);
        *(float2*)((float*)outv + (size_t)dst * TOT + lane * 2) = vv;
    }
}

// ---------------- pooling (batch sorted -> run-compressed atomics) + head ----------------
__global__ __launch_bounds__(256) void pool_kernel(const float* __restrict__ feat,
                                                   const int* __restrict__ batch,
                                                   float* __restrict__ gsum, int n) {
    int t = threadIdx.x;
    int ch = t & 127, half = t >> 7;
    int base = blockIdx.x * 64;
    float acc = 0.f;
    int curg = -1;
    for (int k = half; k < 64; k += 2) {
        int node = base + k;
        if (node >= n) break;
        int g = batch[node];
        if (g != curg) {
            if (curg >= 0) atomicAdd(&gsum[(size_t)curg * 128 + ch], acc);
            acc = 0.f;
            curg = g;
        }
        acc += feat[(size_t)node * 128 + ch];
    }
    if (curg >= 0) atomicAdd(&gsum[(size_t)curg * 128 + ch], acc);
}

__global__ __launch_bounds__(256) void final_kernel(const float* __restrict__ gsum,
                                                    const int* __restrict__ gcnt,
                                                    const float* __restrict__ Wl,
                                                    const float* __restrict__ bl,
                                                    float* __restrict__ out, int g_total) {
    int w = threadIdx.x >> 6, lane = threadIdx.x & 63;
    int g = blockIdx.x * 4 + w;
    if (g >= g_total) return;
    float inv = 1.f / fmaxf((float)gcnt[g], 1.f);
    float p = 0.f;
    #pragma unroll
    for (int j = 0; j < 2; j++) {
        int ch = lane + 64 * j;
        p += gsum[(size_t)g * 128 + ch] * Wl[ch];
    }
    #pragma unroll
    for (int d = 32; d; d >>= 1) p += __shfl_xor(p, d);
    if (lane == 0) out[g] = p * inv + bl[0];
}

extern "C" void kernel_launch(void* const* d_in, const int* in_sizes, int n_in,
                              void* d_out, int out_size, void* d_ws, size_t ws_size,
                              hipStream_t stream) {
    const float* x   = (const float*)d_in[0];
    const int*   ei  = (const int*)d_in[1];
    const int*   bat = (const int*)d_in[2];
    const float* W1  = (const float*)d_in[3];
    const float* as1 = (const float*)d_in[4];
    const float* ad1 = (const float*)d_in[5];
    const float* b1  = (const float*)d_in[6];
    const float* W2  = (const float*)d_in[7];
    const float* as2 = (const float*)d_in[8];
    const float* ad2 = (const float*)d_in[9];
    const float* b2  = (const float*)d_in[10];
    const float* Wl  = (const float*)d_in[11];
    const float* bl  = (const float*)d_in[12];
    float* out = (float*)d_out;

    const int N    = in_sizes[0] / 128;
    const int E    = in_sizes[1] / 2;
    const int Et   = E + N;
    const int G    = 512;
    const int Mpad = (N + 127) & ~127;
    const int nb   = (N + 1023) >> 10;

    char* p = (char*)d_ws;
    auto alloc = [&](size_t bytes) { char* r = p; p += (bytes + 255) & ~(size_t)255; return r; };
    ushort_t* xb    = (ushort_t*)alloc((size_t)Mpad * 128 * 2);
    ushort_t* W1t   = (ushort_t*)alloc((size_t)512 * 128 * 2);
    ushort_t* W2t   = (ushort_t*)alloc((size_t)128 * 512 * 2);
    ushort_t* h1b   = (ushort_t*)alloc((size_t)Mpad * 512 * 2);
    ushort_t* hb    = (ushort_t*)alloc((size_t)Mpad * 512 * 2);
    ushort_t* h2b   = (ushort_t*)alloc((size_t)Mpad * 128 * 2);
    float*    feat2 = (float*)alloc((size_t)N * 128 * 4);
    // ---- zeroed block (one memset) ----
    float*    avs1  = (float*)alloc((size_t)Mpad * 4 * 4);
    float*    avd1  = (float*)alloc((size_t)Mpad * 4 * 4);
    float*    avs2  = (float*)alloc((size_t)Mpad * 4);
    float*    avd2  = (float*)alloc((size_t)Mpad * 4);
    float*    gsum  = (float*)alloc((size_t)G * 128 * 4);
    int*      gcnt  = (int*)alloc((size_t)G * 4);
    int*      deg   = (int*)alloc((size_t)N * 4);
    // ---- end zeroed block ----
    int*      off   = (int*)alloc((size_t)(N + 1) * 4);
    int*      cur   = (int*)alloc((size_t)N * 4);
    int*      btot  = (int*)alloc((size_t)64 * 4);
    int*      csr   = (int*)alloc((size_t)Et * 4);

    hipMemsetAsync(avs1, 0, (size_t)((char*)off - (char*)avs1), stream);
    hipMemsetAsync(hb + (size_t)N * 512, 0, (size_t)(Mpad - N) * 512 * 2, stream);

    // CSR by dst (shared by both layers)
    hist_kernel<<<(Et + 255) / 256, 256, 0, stream>>>(ei, E, Et, deg);
    scan_local<<<nb, 1024, 0, stream>>>(deg, off, btot, N);
    scan_base<<<1, 64, 0, stream>>>(btot, nb);
    scan_add<<<(N + 256) / 256, 256, 0, stream>>>(btot, off, cur, bat, gcnt, N, nb);
    cast_all<<<((Mpad * 128 + 2 * 65536) + 255) / 256, 256, 0, stream>>>(x, W1, W2, xb, W1t, W2t,
                                                                         N * 128, Mpad * 128);
    scatter_kernel<<<(Et + 255) / 256, 256, 0, stream>>>(ei, E, Et, cur, csr);

    // Layer 1: GEMM (+fused avec) then softmax-aggregate (+bias+ELU)
    gemm_bf16<4, 4><<<dim3(Mpad / 128, 4), 256, 0, stream>>>(xb, W1t, h1b, as1, ad1, avs1, avd1, 128, 512);
    agg_kernel<4, 512, true><<<(N + 3) / 4, 256, 0, stream>>>(off, csr, h1b, avs1, avd1, b1, hb, N);

    // Layer 2
    gemm_bf16<2, 1><<<dim3(Mpad / 64, 1), 256, 0, stream>>>(hb, W2t, h2b, as2, ad2, avs2, avd2, 512, 128);
    agg_kernel<1, 128, false><<<(N + 3) / 4, 256, 0, stream>>>(off, csr, h2b, avs2, avd2, b2, feat2, N);

    // Pool + head
    pool_kernel<<<(N + 63) / 64, 256, 0, stream>>>(feat2, bat, gsum, N);
    final_kernel<<<(G + 3) / 4, 256, 0, stream>>>(gsum, gcnt, Wl, bl, out, G);
}

// Round 4
// 441.715 us; speedup vs baseline: 2.0305x; 1.1355x over previous
//
#include <hip/hip_runtime.h>
#include <math.h>

#define NEG_SLOPE 0.2f

typedef float f4 __attribute__((ext_vector_type(4)));
typedef __attribute__((ext_vector_type(8))) short short8;   // 8 bf16 (4 VGPRs)
typedef __attribute__((ext_vector_type(4))) float f32x4;
typedef unsigned short ushort_t;
typedef unsigned char uchar_t;

__device__ __forceinline__ float bf2f(unsigned short s) {
    unsigned u = ((unsigned)s) << 16;
    float f; __builtin_memcpy(&f, &u, 4); return f;
}
__device__ __forceinline__ unsigned short f2bf(float f) {
    unsigned u; __builtin_memcpy(&u, &f, 4);
    u = (u + 0x7FFFu + ((u >> 16) & 1u)) >> 16;   // RNE
    return (unsigned short)u;
}
__device__ __forceinline__ void gload16(const void* g, void* l) {
    __builtin_amdgcn_global_load_lds((const __attribute__((address_space(1))) void*)g,
                                     (__attribute__((address_space(3))) void*)l, 16, 0, 0);
}

// ---------------- CSR build ----------------
__global__ void hist_kernel(const int* __restrict__ ei, int E, int Et, int* __restrict__ deg) {
    int e = blockIdx.x * blockDim.x + threadIdx.x;
    if (e >= Et) return;
    int d = (e < E) ? ei[E + e] : (e - E);
    atomicAdd(&deg[d], 1);
}

__global__ __launch_bounds__(1024) void scan_local(const int* __restrict__ deg,
                                                   int* __restrict__ off,
                                                   int* __restrict__ btot, int n) {
    __shared__ int s_w[16];
    int tid = threadIdx.x, lane = tid & 63, wv = tid >> 6;
    int i = blockIdx.x * 1024 + tid;
    int v = (i < n) ? deg[i] : 0;
    int x = v;
    #pragma unroll
    for (int d = 1; d < 64; d <<= 1) {
        int y = __shfl_up(x, d);
        if (lane >= d) x += y;
    }
    if (lane == 63) s_w[wv] = x;
    __syncthreads();
    if (tid < 16) {
        int y = s_w[tid];
        int z = y;
        #pragma unroll
        for (int d = 1; d < 16; d <<= 1) {
            int t2 = __shfl_up(z, d);
            if (tid >= d) z += t2;
        }
        if (tid == 15) btot[blockIdx.x] = z;
        s_w[tid] = z - y;
    }
    __syncthreads();
    if (i < n) off[i] = s_w[wv] + (x - v);
}

__global__ void scan_base(int* __restrict__ btot, int nb) {
    int lane = threadIdx.x;
    int v = (lane < nb) ? btot[lane] : 0;
    int x = v;
    #pragma unroll
    for (int d = 1; d < 64; d <<= 1) {
        int y = __shfl_up(x, d);
        if (lane >= d) x += y;
    }
    int total = __shfl(x, nb - 1);
    if (lane < nb) btot[lane] = x - v;
    if (lane == 0) btot[nb] = total;
}

__global__ void scan_add(const int* __restrict__ btot, int* __restrict__ off,
                         int* __restrict__ cur, const int* __restrict__ batch,
                         int* __restrict__ gcnt, int n, int nb) {
    int i = blockIdx.x * blockDim.x + threadIdx.x;
    if (i < n) {
        int o = off[i] + btot[i >> 10];
        off[i] = o;
        cur[i] = o;
        atomicAdd(&gcnt[batch[i]], 1);
    } else if (i == n) {
        off[n] = btot[nb];
    }
}

__global__ void scatter_kernel(const int* __restrict__ ei, int E, int Et,
                               int* __restrict__ cur, int* __restrict__ csr) {
    int e = blockIdx.x * blockDim.x + threadIdx.x;
    if (e >= Et) return;
    int s, d;
    if (e < E) { s = ei[e]; d = ei[E + e]; }
    else       { s = d = e - E; }
    int p = atomicAdd(&cur[d], 1);
    csr[p] = s;
}

// ---------------- fused casts: x -> bf16 (padded), W1/W2 -> transposed bf16 ----------------
__global__ void cast_all(const float* __restrict__ x, const float* __restrict__ W1,
                         const float* __restrict__ W2, ushort_t* __restrict__ xb,
                         ushort_t* __restrict__ W1t, ushort_t* __restrict__ W2t,
                         int n_x, int pad_x) {
    int i = blockIdx.x * blockDim.x + threadIdx.x;
    if (i < pad_x) {
        xb[i] = f2bf(i < n_x ? x[i] : 0.f);
        return;
    }
    int k = i - pad_x;
    if (k < 128 * 512) {                 // W1 [128][512] -> W1t [512][128]
        int r = k >> 9, c = k & 511;
        W1t[(size_t)c * 128 + r] = f2bf(W1[k]);
        return;
    }
    k -= 128 * 512;
    if (k < 512 * 128) {                 // W2 [512][128] -> W2t [128][512]
        int r = k >> 7, c = k & 127;
        W2t[(size_t)c * 512 + r] = f2bf(W2[k]);
    }
}

// ---------------- bf16 MFMA GEMM, full-width rows, quantized int8 output ----------------
// C[M,BN] = A[M,K] @ Bt[BN,K]^T. BM=32, BN=full output width, BK=32, 4 waves each
// owning BN/4 cols. Epilogue (all in one block per 32 rows):
//   rowmax -> scale (f32 per row), int8 quant (+128 bias, packed via LDS),
//   avs/avd = C . aw  (direct store; cross-wave LDS reduce for H==1).
template<int BN, int H>
__global__ __launch_bounds__(256) void gemm_q(const ushort_t* __restrict__ A,
                                              const ushort_t* __restrict__ Bt,
                                              uchar_t* __restrict__ Cq,
                                              float* __restrict__ Csc,
                                              const float* __restrict__ aw_src,
                                              const float* __restrict__ aw_dst,
                                              float* __restrict__ avs,
                                              float* __restrict__ avd,
                                              int K) {
    constexpr int CT = BN / 64;          // col-tiles (16 wide) per wave
    __shared__ __align__(16) ushort_t As[32 * 32];
    __shared__ __align__(16) ushort_t Bs[BN * 32];
    __shared__ float s_rm[4][32];
    __shared__ float s_rs[32];
    __shared__ float s_avp[2][4][32];    // used for H==1 cross-wave reduce
    const int t = threadIdx.x, w = t >> 6, lane = t & 63;
    const int r0 = blockIdx.x * 32;

    const ushort_t* Ag = A + (size_t)(r0 + w * 16 + (lane >> 2)) * K + (lane & 3) * 8;
    const ushort_t* Bg = Bt + (size_t)(w * (BN / 4) + (lane >> 2)) * K + (lane & 3) * 8;
    ushort_t* Al = As + w * 512;
    ushort_t* Bl = Bs + w * (BN / 4) * 32;

    f32x4 acc[2][CT] = {};
    for (int k0 = 0; k0 < K; k0 += 32) {
        __syncthreads();
        if (w < 2) gload16(Ag + k0, Al);
        #pragma unroll
        for (int m = 0; m < CT; m++)
            gload16(Bg + k0 + (size_t)m * 16 * K, Bl + m * 512);
        __syncthreads();
        short8 af[2], bf[CT];
        #pragma unroll
        for (int i = 0; i < 2; i++)
            af[i] = *(const short8*)(As + (i * 16 + (lane & 15)) * 32 + (lane >> 4) * 8);
        #pragma unroll
        for (int jj = 0; jj < CT; jj++)
            bf[jj] = *(const short8*)(Bs + (w * (BN / 4) + jj * 16 + (lane & 15)) * 32 + (lane >> 4) * 8);
        #pragma unroll
        for (int i = 0; i < 2; i++)
            #pragma unroll
            for (int jj = 0; jj < CT; jj++)
                acc[i][jj] = __builtin_amdgcn_mfma_f32_16x16x32_bf16(af[i], bf[jj], acc[i][jj], 0, 0, 0);
    }

    // ---- per-row absmax over this wave's cols, then cross-wave via LDS ----
    float mr[2][4];
    #pragma unroll
    for (int i = 0; i < 2; i++)
        #pragma unroll
        for (int r = 0; r < 4; r++) {
            float m = 0.f;
            #pragma unroll
            for (int jj = 0; jj < CT; jj++) m = fmaxf(m, fabsf(acc[i][jj][r]));
            mr[i][r] = m;
        }
    #pragma unroll
    for (int d = 1; d < 16; d <<= 1)
        #pragma unroll
        for (int i = 0; i < 2; i++)
            #pragma unroll
            for (int r = 0; r < 4; r++) mr[i][r] = fmaxf(mr[i][r], __shfl_xor(mr[i][r], d));
    if ((lane & 15) == 0) {
        #pragma unroll
        for (int i = 0; i < 2; i++)
            #pragma unroll
            for (int r = 0; r < 4; r++) s_rm[w][i * 16 + (lane >> 4) * 4 + r] = mr[i][r];
    }

    // ---- fused attention dots (exact f32, pre-quant) ----
    float asc[CT], adc[CT];
    #pragma unroll
    for (int jj = 0; jj < CT; jj++) {
        int c = w * (BN / 4) + jj * 16 + (lane & 15);
        asc[jj] = aw_src[c];
        adc[jj] = aw_dst[c];
    }
    #pragma unroll
    for (int i = 0; i < 2; i++) {
        #pragma unroll
        for (int r = 0; r < 4; r++) {
            float ps = 0.f, pd = 0.f;
            #pragma unroll
            for (int jj = 0; jj < CT; jj++) {
                float v = acc[i][jj][r];
                ps = fmaf(v, asc[jj], ps);
                pd = fmaf(v, adc[jj], pd);
            }
            #pragma unroll
            for (int d = 1; d < 16; d <<= 1) {
                ps += __shfl_xor(ps, d);
                pd += __shfl_xor(pd, d);
            }
            if ((lane & 15) == 0) {
                int row = i * 16 + (lane >> 4) * 4 + r;
                if constexpr (H == 4) {     // wave w == head w (cols w*128..)
                    avs[(size_t)(r0 + row) * 4 + w] = ps;
                    avd[(size_t)(r0 + row) * 4 + w] = pd;
                } else {
                    s_avp[0][w][row] = ps;
                    s_avp[1][w][row] = pd;
                }
            }
        }
    }
    __syncthreads();
    if (t < 32) {
        float rm = fmaxf(fmaxf(s_rm[0][t], s_rm[1][t]), fmaxf(s_rm[2][t], s_rm[3][t]));
        rm = fmaxf(rm, 1e-30f);
        Csc[r0 + t] = rm * (1.f / 127.f);
        s_rs[t] = 127.f / rm;
        if constexpr (H == 1) {
            avs[r0 + t] = s_avp[0][0][t] + s_avp[0][1][t] + s_avp[0][2][t] + s_avp[0][3][t];
            avd[r0 + t] = s_avp[1][0][t] + s_avp[1][1][t] + s_avp[1][2][t] + s_avp[1][3][t];
        }
    }
    __syncthreads();
    // ---- quantize into LDS (reuse Bs), then coalesced write-out ----
    uchar_t* s_q = (uchar_t*)Bs;
    #pragma unroll
    for (int i = 0; i < 2; i++)
        #pragma unroll
        for (int jj = 0; jj < CT; jj++)
            #pragma unroll
            for (int r = 0; r < 4; r++) {
                int row = i * 16 + (lane >> 4) * 4 + r;
                int col = w * (BN / 4) + jj * 16 + (lane & 15);
                int qi = (int)rintf(acc[i][jj][r] * s_rs[row]) + 128;
                qi = min(255, max(0, qi));
                s_q[row * BN + col] = (uchar_t)qi;
            }
    __syncthreads();
    constexpr int PASSES = BN / 128;                 // 32*BN bytes / 4096 per pass
    constexpr int CPR = BN / 16;                     // 16B chunks per row
    #pragma unroll
    for (int p2 = 0; p2 < PASSES; p2++) {
        int idx = p2 * 256 + t;
        int row = idx / CPR, ch = idx % CPR;
        *(uint4*)(Cq + (size_t)(r0 + row) * BN + ch * 16) =
            *(const uint4*)(s_q + row * BN + ch * 16);
    }
}

// ---------------- single-pass edge softmax + aggregation over int8 features ----------------
// out = (sum_e e_e * s_src * (qu-128)) / (sum_e e_e); den & S=sum(e*s) hoisted to chunk phase.
template<int H, int TOT, bool OUT_BF16>
__global__ __launch_bounds__(256) void agg_q(const int* __restrict__ off,
                                             const int* __restrict__ csr,
                                             const uchar_t* __restrict__ fq,
                                             const float* __restrict__ fs,
                                             const float* __restrict__ avs,
                                             const float* __restrict__ avd,
                                             const float* __restrict__ bias,
                                             void* __restrict__ outv, int n) {
    constexpr int J = TOT / 64;          // bytes per lane per edge
    __shared__ float s_ex[4][64 * H];
    int w = threadIdx.x >> 6, lane = threadIdx.x & 63;
    int dst = blockIdx.x * 4 + w;
    if (dst >= n) return;
    const int h_own = (H == 1) ? 0 : (lane >> 4);
    float adv[H];
    if constexpr (H == 4) {
        f4 t4 = *(const f4*)&avd[(size_t)dst * 4];
        #pragma unroll
        for (int h = 0; h < 4; h++) adv[h] = t4[h];
    } else {
        adv[0] = avd[dst];
    }
    int beg = off[dst], end = off[dst + 1];
    float den[H] = {}, Ssum[H] = {};
    float acc[J] = {};
    float* exw = s_ex[w];

    for (int b = beg; b < end; b += 64) {
        int idx = b + lane;
        bool val = idx < end;
        int sv = val ? csr[idx] : 0;
        float srow = fs[sv];
        unsigned myoff = (unsigned)sv * TOT;
        if constexpr (H == 4) {
            f4 av = *(const f4*)&avs[(size_t)sv * 4];
            f4 exv;
            #pragma unroll
            for (int h = 0; h < 4; h++) {
                float l = av[h] + adv[h];
                l = fmaxf(l, l * NEG_SLOPE);           // leaky_relu (slope<1)
                float e = val ? __expf(l) : 0.f;
                den[h] += e;
                float es = e * srow;
                Ssum[h] += es;
                exv[h] = es;
            }
            *(f4*)&exw[lane * 4] = exv;
        } else {
            float l = avs[sv] + adv[0];
            l = fmaxf(l, l * NEG_SLOPE);
            float e = val ? __expf(l) : 0.f;
            den[0] += e;
            float es = e * srow;
            Ssum[0] += es;
            exw[lane] = es;
        }
        asm volatile("s_waitcnt lgkmcnt(0)" ::: "memory");
        int cnt = min(64, end - b);
        int j = 0;
        for (; j + 2 <= cnt; j += 2) {
            float e0 = exw[j * H + h_own];
            float e1 = exw[(j + 1) * H + h_own];
            unsigned v0 = (unsigned)__shfl((int)myoff, j) + lane * J;
            unsigned v1 = (unsigned)__shfl((int)myoff, j + 1) + lane * J;
            if constexpr (J == 8) {
                uint2 u0 = *(const uint2*)(fq + v0);
                uint2 u1 = *(const uint2*)(fq + v1);
                acc[0] += e0 * (float)(u0.x & 0xffu);
                acc[1] += e0 * (float)((u0.x >> 8) & 0xffu);
                acc[2] += e0 * (float)((u0.x >> 16) & 0xffu);
                acc[3] += e0 * (float)(u0.x >> 24);
                acc[4] += e0 * (float)(u0.y & 0xffu);
                acc[5] += e0 * (float)((u0.y >> 8) & 0xffu);
                acc[6] += e0 * (float)((u0.y >> 16) & 0xffu);
                acc[7] += e0 * (float)(u0.y >> 24);
                acc[0] += e1 * (float)(u1.x & 0xffu);
                acc[1] += e1 * (float)((u1.x >> 8) & 0xffu);
                acc[2] += e1 * (float)((u1.x >> 16) & 0xffu);
                acc[3] += e1 * (float)(u1.x >> 24);
                acc[4] += e1 * (float)(u1.y & 0xffu);
                acc[5] += e1 * (float)((u1.y >> 8) & 0xffu);
                acc[6] += e1 * (float)((u1.y >> 16) & 0xffu);
                acc[7] += e1 * (float)(u1.y >> 24);
            } else {
                unsigned us0 = *(const ushort_t*)(fq + v0);
                unsigned us1 = *(const ushort_t*)(fq + v1);
                acc[0] += e0 * (float)(us0 & 0xffu);
                acc[1] += e0 * (float)(us0 >> 8);
                acc[0] += e1 * (float)(us1 & 0xffu);
                acc[1] += e1 * (float)(us1 >> 8);
            }
        }
        if (j < cnt) {
            float e0 = exw[j * H + h_own];
            unsigned v0 = (unsigned)__shfl((int)myoff, j) + lane * J;
            if constexpr (J == 8) {
                uint2 u0 = *(const uint2*)(fq + v0);
                acc[0] += e0 * (float)(u0.x & 0xffu);
                acc[1] += e0 * (float)((u0.x >> 8) & 0xffu);
                acc[2] += e0 * (float)((u0.x >> 16) & 0xffu);
                acc[3] += e0 * (float)(u0.x >> 24);
                acc[4] += e0 * (float)(u0.y & 0xffu);
                acc[5] += e0 * (float)((u0.y >> 8) & 0xffu);
                acc[6] += e0 * (float)((u0.y >> 16) & 0xffu);
                acc[7] += e0 * (float)(u0.y >> 24);
            } else {
                unsigned us0 = *(const ushort_t*)(fq + v0);
                acc[0] += e0 * (float)(us0 & 0xffu);
                acc[1] += e0 * (float)(us0 >> 8);
            }
        }
    }
    // wave-reduce den and S (per head)
    #pragma unroll
    for (int h = 0; h < H; h++) {
        #pragma unroll
        for (int d = 32; d; d >>= 1) {
            den[h] += __shfl_xor(den[h], d);
            Ssum[h] += __shfl_xor(Ssum[h], d);
        }
    }
    float dh, Sh;
    if constexpr (H == 4) {
        dh = (lane & 32) ? ((lane & 16) ? den[3] : den[2]) : ((lane & 16) ? den[1] : den[0]);
        Sh = (lane & 32) ? ((lane & 16) ? Ssum[3] : Ssum[2]) : ((lane & 16) ? Ssum[1] : Ssum[0]);
    } else {
        dh = den[0]; Sh = Ssum[0];
    }
    float rden = 1.f / dh;
    if constexpr (OUT_BF16) {
        unsigned short ov[J];
        #pragma unroll
        for (int u = 0; u < J; u++) {
            float v = (acc[u] - 128.f * Sh) * rden + bias[lane * J + u];
            v = v > 0.f ? v : expm1f(v);
            ov[u] = f2bf(v);
        }
        *(short8*)((ushort_t*)outv + (size_t)dst * TOT + lane * J) = *(short8*)ov;
    } else {
        float v0 = (acc[0] - 128.f * Sh) * rden + bias[lane * 2];
        float v1 = (acc[1] - 128.f * Sh) * rden + bias[lane * 2 + 1];
        v0 = v0 > 0.f ? v0 : expm1f(v0);
        v1 = v1 > 0.f ? v1 : expm1f(v1);
        float2 vv = make_float2(v0, v1);
        *(float2*)((float*)outv + (size_t)dst * TOT + lane * 2) = vv;
    }
}

// ---------------- pooling (batch sorted -> run-compressed atomics) + head ----------------
__global__ __launch_bounds__(256) void pool_kernel(const float* __restrict__ feat,
                                                   const int* __restrict__ batch,
                                                   float* __restrict__ gsum, int n) {
    int t = threadIdx.x;
    int ch = t & 127, half = t >> 7;
    int base = blockIdx.x * 64;
    float acc = 0.f;
    int curg = -1;
    for (int k = half; k < 64; k += 2) {
        int node = base + k;
        if (node >= n) break;
        int g = batch[node];
        if (g != curg) {
            if (curg >= 0) atomicAdd(&gsum[(size_t)curg * 128 + ch], acc);
            acc = 0.f;
            curg = g;
        }
        acc += feat[(size_t)node * 128 + ch];
    }
    if (curg >= 0) atomicAdd(&gsum[(size_t)curg * 128 + ch], acc);
}

__global__ __launch_bounds__(256) void final_kernel(const float* __restrict__ gsum,
                                                    const int* __restrict__ gcnt,
                                                    const float* __restrict__ Wl,
                                                    const float* __restrict__ bl,
                                                    float* __restrict__ out, int g_total) {
    int w = threadIdx.x >> 6, lane = threadIdx.x & 63;
    int g = blockIdx.x * 4 + w;
    if (g >= g_total) return;
    float inv = 1.f / fmaxf((float)gcnt[g], 1.f);
    float p = 0.f;
    #pragma unroll
    for (int j = 0; j < 2; j++) {
        int ch = lane + 64 * j;
        p += gsum[(size_t)g * 128 + ch] * Wl[ch];
    }
    #pragma unroll
    for (int d = 32; d; d >>= 1) p += __shfl_xor(p, d);
    if (lane == 0) out[g] = p * inv + bl[0];
}

extern "C" void kernel_launch(void* const* d_in, const int* in_sizes, int n_in,
                              void* d_out, int out_size, void* d_ws, size_t ws_size,
                              hipStream_t stream) {
    const float* x   = (const float*)d_in[0];
    const int*   ei  = (const int*)d_in[1];
    const int*   bat = (const int*)d_in[2];
    const float* W1  = (const float*)d_in[3];
    const float* as1 = (const float*)d_in[4];
    const float* ad1 = (const float*)d_in[5];
    const float* b1  = (const float*)d_in[6];
    const float* W2  = (const float*)d_in[7];
    const float* as2 = (const float*)d_in[8];
    const float* ad2 = (const float*)d_in[9];
    const float* b2  = (const float*)d_in[10];
    const float* Wl  = (const float*)d_in[11];
    const float* bl  = (const float*)d_in[12];
    float* out = (float*)d_out;

    const int N    = in_sizes[0] / 128;
    const int E    = in_sizes[1] / 2;
    const int Et   = E + N;
    const int G    = 512;
    const int Mpad = (N + 127) & ~127;
    const int nb   = (N + 1023) >> 10;

    char* p = (char*)d_ws;
    auto alloc = [&](size_t bytes) { char* r = p; p += (bytes + 255) & ~(size_t)255; return r; };
    ushort_t* xb    = (ushort_t*)alloc((size_t)Mpad * 128 * 2);
    ushort_t* W1t   = (ushort_t*)alloc((size_t)512 * 128 * 2);
    ushort_t* W2t   = (ushort_t*)alloc((size_t)128 * 512 * 2);
    uchar_t*  h1q   = (uchar_t*)alloc((size_t)Mpad * 512);
    float*    h1s   = (float*)alloc((size_t)Mpad * 4);
    ushort_t* hb    = (ushort_t*)alloc((size_t)Mpad * 512 * 2);
    uchar_t*  h2q   = (uchar_t*)alloc((size_t)Mpad * 128);
    float*    h2s   = (float*)alloc((size_t)Mpad * 4);
    float*    feat2 = (float*)alloc((size_t)N * 128 * 4);
    float*    avs1  = (float*)alloc((size_t)Mpad * 4 * 4);
    float*    avd1  = (float*)alloc((size_t)Mpad * 4 * 4);
    float*    avs2  = (float*)alloc((size_t)Mpad * 4);
    float*    avd2  = (float*)alloc((size_t)Mpad * 4);
    // ---- zeroed block (one memset) ----
    float*    gsum  = (float*)alloc((size_t)G * 128 * 4);
    int*      gcnt  = (int*)alloc((size_t)G * 4);
    int*      deg   = (int*)alloc((size_t)N * 4);
    // ---- end zeroed block ----
    int*      off   = (int*)alloc((size_t)(N + 1) * 4);
    int*      cur   = (int*)alloc((size_t)N * 4);
    int*      btot  = (int*)alloc((size_t)128 * 4);
    int*      csr   = (int*)alloc((size_t)Et * 4);

    hipMemsetAsync(gsum, 0, (size_t)((char*)off - (char*)gsum), stream);
    hipMemsetAsync(hb + (size_t)N * 512, 0, (size_t)(Mpad - N) * 512 * 2, stream);

    // CSR by dst (shared by both layers)
    hist_kernel<<<(Et + 255) / 256, 256, 0, stream>>>(ei, E, Et, deg);
    scan_local<<<nb, 1024, 0, stream>>>(deg, off, btot, N);
    scan_base<<<1, 64, 0, stream>>>(btot, nb);
    scan_add<<<(N + 256) / 256, 256, 0, stream>>>(btot, off, cur, bat, gcnt, N, nb);
    cast_all<<<((Mpad * 128 + 2 * 65536) + 255) / 256, 256, 0, stream>>>(x, W1, W2, xb, W1t, W2t,
                                                                         N * 128, Mpad * 128);
    scatter_kernel<<<(Et + 255) / 256, 256, 0, stream>>>(ei, E, Et, cur, csr);

    // Layer 1: GEMM (+rowscale int8 quant + fused avec), then softmax-aggregate (+bias+ELU)
    gemm_q<512, 4><<<Mpad / 32, 256, 0, stream>>>(xb, W1t, h1q, h1s, as1, ad1, avs1, avd1, 128);
    agg_q<4, 512, true><<<(N + 3) / 4, 256, 0, stream>>>(off, csr, h1q, h1s, avs1, avd1, b1, hb, N);

    // Layer 2
    gemm_q<128, 1><<<Mpad / 32, 256, 0, stream>>>(hb, W2t, h2q, h2s, as2, ad2, avs2, avd2, 512);
    agg_q<1, 128, false><<<(N + 3) / 4, 256, 0, stream>>>(off, csr, h2q, h2s, avs2, avd2, b2, feat2, N);

    // Pool + head
    pool_kernel<<<(N + 63) / 64, 256, 0, stream>>>(feat2, bat, gsum, N);
    final_kernel<<<(G + 3) / 4, 256, 0, stream>>>(gsum, gcnt, Wl, bl, out, G);
}